// Round 14
// baseline (206.292 us; speedup 1.0000x reference)
//
#include <hip/hip_runtime.h>
#include <stdint.h>

#define NB 4
#define SS 1024
#define DD 1024
#define EE 4
#define HH 16
#define HDD 64
#define NN (NB*SS)      // 4096 tokens
#define KK2 (EE*DD)     // 4096 expanded K
#define FF1 (3*DD)      // 3072

typedef __attribute__((ext_vector_type(4))) float f32x4;
typedef __attribute__((ext_vector_type(8))) _Float16 half8;
typedef __attribute__((ext_vector_type(4))) _Float16 half4;

static __device__ __forceinline__ f32x4 mfma16(half8 a, half8 b, f32x4 c){
  return __builtin_amdgcn_mfma_f32_16x16x32_f16(a, b, c, 0, 0, 0);
}

// async global->LDS, 16B per lane; LDS dest = wave-uniform base + lane*16
#define GLOAD_LDS16(gp, lp) __builtin_amdgcn_global_load_lds( \
    (const unsigned int __attribute__((address_space(1)))*)(uintptr_t)(gp), \
    (unsigned int __attribute__((address_space(3)))*)(uintptr_t)(lp), 16, 0, 0)

#define SBAR() do { asm volatile("" ::: "memory"); \
                    __builtin_amdgcn_s_barrier(); \
                    asm volatile("" ::: "memory"); } while(0)
#define VMC(n) asm volatile("s_waitcnt vmcnt(" #n ")" ::: "memory")

// ---------------- fused prologue: W transposes + router/LN prep -------------
__device__ __forceinline__ void prep_body(
    const float* __restrict__ x, const float* __restrict__ Wr,
    const float* __restrict__ br, float* __restrict__ score,
    float* __restrict__ ratios, _Float16* __restrict__ xnb,
    int n, float (*red)[6])
{
  int tid = threadIdx.x;
  float4 xv = ((const float4*)(x + (size_t)n*DD))[tid];   // d = tid*4..+3
  float xa[4] = {xv.x, xv.y, xv.z, xv.w};
  float vals[6];
  vals[0] = xa[0]+xa[1]+xa[2]+xa[3];
  vals[1] = xa[0]*xa[0]+xa[1]*xa[1]+xa[2]*xa[2]+xa[3]*xa[3];
  vals[2] = vals[3] = vals[4] = vals[5] = 0.f;
  #pragma unroll
  for (int j = 0; j < 4; ++j){
    float4 w = ((const float4*)Wr)[tid*4 + j];
    vals[2] += xa[j]*w.x; vals[3] += xa[j]*w.y;
    vals[4] += xa[j]*w.z; vals[5] += xa[j]*w.w;
  }
  #pragma unroll
  for (int off = 32; off >= 1; off >>= 1)
    #pragma unroll
    for (int i = 0; i < 6; ++i)
      vals[i] += __shfl_xor(vals[i], off, 64);
  int wid = tid >> 6;
  if ((tid & 63) == 0){
    #pragma unroll
    for (int i = 0; i < 6; ++i) red[wid][i] = vals[i];
  }
  __syncthreads();
  float tot[6];
  #pragma unroll
  for (int i = 0; i < 6; ++i)
    tot[i] = red[0][i] + red[1][i] + red[2][i] + red[3][i];

  float mu   = tot[0] * (1.f/DD);
  float var  = tot[1] * (1.f/DD) - mu*mu;
  float rsig = rsqrtf(var + 1e-5f);
  float lg[4];
  #pragma unroll
  for (int e = 0; e < 4; ++e) lg[e] = tot[2+e] + br[e];
  float mx = fmaxf(fmaxf(lg[0], lg[1]), fmaxf(lg[2], lg[3]));
  float ex[4], esum = 0.f;
  #pragma unroll
  for (int e = 0; e < 4; ++e){ ex[e] = __expf(lg[e] - mx); esum += ex[e]; }
  if (tid < 4){
    score[n*4 + tid] = ex[tid] / esum;
    // expert-major telescoping: ratio[e] = s_{e-1}/s_e (e>=1)
    ratios[n*4 + tid] = (tid > 0) ? (ex[tid-1] / ex[tid]) : 0.f;
  }

  half4 o;
  #pragma unroll
  for (int j = 0; j < 4; ++j) o[j] = (_Float16)((xa[j] - mu) * rsig);
  *(half4*)(xnb + (size_t)n*DD + tid*4) = o;
}

template<bool AFFINE>
__device__ __forceinline__ void transpose_body(
    const float* __restrict__ W, _Float16* __restrict__ WT, int K, int F,
    const float* __restrict__ gvec, const float* __restrict__ bvec,
    float* __restrict__ part, int k0, int f0,
    float (*t)[65], float (*red2)[64])
{
  int tid = threadIdx.x;
  int r = tid >> 4, c4 = (tid & 15) * 4;
  float pf[4] = {0.f, 0.f, 0.f, 0.f};
  #pragma unroll
  for (int i = 0; i < 4; ++i){
    int k = k0 + i*16 + r;
    float4 v = *(const float4*)(W + (size_t)k*F + f0 + c4);
    if constexpr (AFFINE){
      float bk = bvec[k];
      pf[0] += bk*v.x; pf[1] += bk*v.y; pf[2] += bk*v.z; pf[3] += bk*v.w;
      float gk = gvec[k];
      v.x *= gk; v.y *= gk; v.z *= gk; v.w *= gk;
    }
    t[i*16 + r][c4+0] = v.x; t[i*16 + r][c4+1] = v.y;
    t[i*16 + r][c4+2] = v.z; t[i*16 + r][c4+3] = v.w;
  }
  if constexpr (AFFINE){
    #pragma unroll
    for (int j = 0; j < 4; ++j) red2[r][c4+j] = pf[j];
  }
  __syncthreads();
  int f = tid >> 2, seg = tid & 3;
  half8 o0, o1;
  #pragma unroll
  for (int j = 0; j < 8; ++j){
    o0[j] = (_Float16)t[seg*16 + j][f];
    o1[j] = (_Float16)t[seg*16 + 8 + j][f];
  }
  _Float16* dst = WT + (size_t)(f0 + f)*K + k0 + seg*16;
  *(half8*)dst = o0;
  *(half8*)(dst + 8) = o1;
  if constexpr (AFFINE){
    if (tid < 64){
      float s = 0.f;
      #pragma unroll
      for (int rr = 0; rr < 16; ++rr) s += red2[rr][tid];
      part[(size_t)(k0/64) * F + f0 + tid] = s;
    }
  }
}

__global__ __launch_bounds__(256) void prep_fused_kernel(
    const float* __restrict__ W1, _Float16* __restrict__ W1T,
    const float* __restrict__ W2, _Float16* __restrict__ W2T,
    const float* __restrict__ gvec, const float* __restrict__ bvec,
    float* __restrict__ part,
    const float* __restrict__ x, const float* __restrict__ Wr,
    const float* __restrict__ br, float* __restrict__ score,
    float* __restrict__ ratios, _Float16* __restrict__ xnb)
{
  __shared__ float t[64][65];
  __shared__ float red2[16][64];
  __shared__ float red[4][6];
  int id = blockIdx.x;
  if (id & 1){
    prep_body(x, Wr, br, score, ratios, xnb, id >> 1, red);
  } else {
    int tr = id >> 1;
    int k0 = (tr & 63) * 64;
    int y  = tr >> 6;
    if (y < FF1/64)
      transpose_body<true >(W1, W1T, KK2, FF1, gvec, bvec, part, k0, y*64, t, red2);
    else
      transpose_body<false>(W2, W2T, KK2, DD, nullptr, nullptr, nullptr,
                            k0, (y - FF1/64)*64, t, red2);
  }
}

// ---------------- BB1[e,f] = b_attn[e,f] + sum_i part[e*16+i, f] ------------
__global__ __launch_bounds__(256) void bb1_kernel(
    const float* __restrict__ b_attn, const float* __restrict__ part,
    float* __restrict__ BB1)
{
  int idx = blockIdx.x*256 + threadIdx.x;   // e*FF1 + f
  int e = idx / FF1, f = idx - e*FF1;
  float s = b_attn[idx];
  #pragma unroll
  for (int i = 0; i < 16; ++i)
    s += part[(size_t)(e*16 + i)*FF1 + f];
  BB1[idx] = s;
}

// ---------------- GEMM1: qkv[4096,3072] = sum_e s_e*(xn @ W1g_e) + bias -----
// 128x192 tile, BK=64, 8 waves (2M x 4N, per-wave 64x48). LDS dbuf = 80 KiB
// EXACTLY -> 2 blocks/CU (the lever: inter-block overlap hides the barrier
// rendezvous; m114). Counted vmcnt(2), XOR-swizzle, 2-phase with hoisted
// reads, telescoping score rescale (s3 in epilogue).
#define G1_BM 128
#define G1_BN 192
#define G1_BK 64
#define G1_T  (KK2/G1_BK)            // 64 K-tiles (16 per expert)
#define G1_ABUF (G1_BM*G1_BK)        // 8192 f16  = 16 KiB
#define G1_BBUF (G1_BN*G1_BK)        // 12288 f16 = 24 KiB
#define G1_BUFSZ (G1_ABUF+G1_BBUF)   // 20480 f16 = 40 KiB per buffer

__global__ __launch_bounds__(512, 4) void gemm1_kernel(
    const _Float16* __restrict__ XN, const _Float16* __restrict__ BT,
    const float* __restrict__ score, const float* __restrict__ ratios,
    const float* __restrict__ bias, _Float16* __restrict__ C)
{
  __shared__ _Float16 smem[2*G1_BUFSZ];   // 80 KiB -> 2 blocks/CU
  int tid = threadIdx.x;
  int lane = tid & 63, wid = tid >> 6;
  int q = lane & 15, g = lane >> 4;
  int wr = wid >> 2, wc = wid & 3;        // 2M x 4N
  int xo = (q & 7) << 3;
  int bid = blockIdx.x;                   // 512 blocks
  int xcd = bid & 7, li = bid >> 3;       // li 0..63
  int m0 = (li >> 1) * G1_BM;             // 32 m-tiles
  int n0 = (xcd*2 + (li & 1)) * G1_BN;    // each XCD owns 2 n-cols (3.1MB L2)

  int arow[4], brow[3];
  #pragma unroll
  for (int mf = 0; mf < 4; ++mf) arow[mf] = (wr*64 + mf*16 + q)*64;
  #pragma unroll
  for (int nf = 0; nf < 3; ++nf) brow[nf] = G1_ABUF + (wc*48 + nf*16 + q)*64;
  int soff[2] = { (g*8) ^ xo, (32 + g*8) ^ xo };

  auto stageA = [&](int t, int buf){      // 2 loads
    const int d0 = (t & 15) * G1_BK;
    _Float16* sA = smem + buf*G1_BUFSZ;
    #pragma unroll
    for (int ld = 0; ld < 2; ++ld){
      int c = ld*512 + tid;
      int row = c >> 3;
      int seg = (c & 7) ^ (row & 7);      // inverse-swizzled global source
      GLOAD_LDS16(XN + (size_t)(m0 + row)*DD + d0 + seg*8,
                  sA + (ld*512 + wid*64)*8);
    }
  };
  auto stageB = [&](int t, int buf){      // 3 loads
    const int k0 = t * G1_BK;
    _Float16* sB = smem + buf*G1_BUFSZ + G1_ABUF;
    #pragma unroll
    for (int ld = 0; ld < 3; ++ld){
      int c = ld*512 + tid;
      int row = c >> 3;
      int seg = (c & 7) ^ (row & 7);
      GLOAD_LDS16(BT + (size_t)(n0 + row)*KK2 + k0 + seg*8,
                  sB + (ld*512 + wid*64)*8);
    }
  };

  f32x4 acc[4][3] = {};
  half8 af0[2][2], af2[2][2], bf[3][2];

  stageA(0, 0); stageB(0, 0);             // 5 loads in flight

  for (int t = 0; t < G1_T-1; ++t){
    if (t && (t & 15) == 0){              // expert boundary: acc *= s_{e-1}/s_e
      int e = t >> 4;
      #pragma unroll
      for (int mf = 0; mf < 4; ++mf)
        #pragma unroll
        for (int r = 0; r < 4; ++r){
          int gm = m0 + wr*64 + mf*16 + g*4 + r;
          float ratio = ratios[gm*4 + e];
          #pragma unroll
          for (int nf = 0; nf < 3; ++nf)
            acc[mf][nf][r] *= ratio;
        }
    }
    int buf = t & 1, nxt = buf ^ 1;
    const _Float16* base = smem + buf*G1_BUFSZ;
    stageA(t+1, nxt);                               // +2 -> 7 outstanding
    VMC(2); SBAR();                                 // tile t (oldest 5) landed
    // ---- ph0: read af01 + bf, stage B(t+1), MFMA m01 x n012 ----
    #pragma unroll
    for (int m = 0; m < 2; ++m)
      #pragma unroll
      for (int k = 0; k < 2; ++k)
        af0[m][k] = *(const half8*)(base + arow[m] + soff[k]);
    #pragma unroll
    for (int n = 0; n < 3; ++n)
      #pragma unroll
      for (int k = 0; k < 2; ++k)
        bf[n][k] = *(const half8*)(base + brow[n] + soff[k]);
    stageB(t+1, nxt);
    __builtin_amdgcn_s_setprio(1);
    #pragma unroll
    for (int k = 0; k < 2; ++k)
      #pragma unroll
      for (int m = 0; m < 2; ++m)
        #pragma unroll
        for (int n = 0; n < 3; ++n)
          acc[m][n] = mfma16(af0[m][k], bf[n][k], acc[m][n]);
    __builtin_amdgcn_s_setprio(0);
    // ---- ph1: af23 reads hoisted pre-barrier; MFMA m23 after ----
    #pragma unroll
    for (int m = 0; m < 2; ++m)
      #pragma unroll
      for (int k = 0; k < 2; ++k)
        af2[m][k] = *(const half8*)(base + arow[2+m] + soff[k]);
    SBAR();                                         // all buf(t) reads issued
    __builtin_amdgcn_s_setprio(1);
    #pragma unroll
    for (int k = 0; k < 2; ++k)
      #pragma unroll
      for (int m = 0; m < 2; ++m)
        #pragma unroll
        for (int n = 0; n < 3; ++n)
          acc[2+m][n] = mfma16(af2[m][k], bf[n][k], acc[2+m][n]);
    __builtin_amdgcn_s_setprio(0);
  }
  // ---- last tile (expert 3, no boundary) ----
  {
    const _Float16* base = smem + ((G1_T-1) & 1)*G1_BUFSZ;
    VMC(0); SBAR();
    #pragma unroll
    for (int m = 0; m < 2; ++m)
      #pragma unroll
      for (int k = 0; k < 2; ++k){
        af0[m][k] = *(const half8*)(base + arow[m] + soff[k]);
        af2[m][k] = *(const half8*)(base + arow[2+m] + soff[k]);
      }
    #pragma unroll
    for (int n = 0; n < 3; ++n)
      #pragma unroll
      for (int k = 0; k < 2; ++k)
        bf[n][k] = *(const half8*)(base + brow[n] + soff[k]);
    #pragma unroll
    for (int k = 0; k < 2; ++k)
      #pragma unroll
      for (int m = 0; m < 2; ++m)
        #pragma unroll
        for (int n = 0; n < 3; ++n){
          acc[m][n]   = mfma16(af0[m][k], bf[n][k], acc[m][n]);
          acc[2+m][n] = mfma16(af2[m][k], bf[n][k], acc[2+m][n]);
        }
  }

  // epilogue: v = acc*s3 + sum_e score[m,e]*BB1[e,n], f16 store
  float bv[3][4];
  #pragma unroll
  for (int nf = 0; nf < 3; ++nf){
    int gn = n0 + wc*48 + nf*16 + q;
    #pragma unroll
    for (int e = 0; e < 4; ++e) bv[nf][e] = bias[e*FF1 + gn];
  }
  #pragma unroll
  for (int mf = 0; mf < 4; ++mf){
    #pragma unroll
    for (int r = 0; r < 4; ++r){
      int gm = m0 + wr*64 + mf*16 + g*4 + r;
      float4 sc = *(const float4*)(score + gm*4);
      #pragma unroll
      for (int nf = 0; nf < 3; ++nf){
        int gn = n0 + wc*48 + nf*16 + q;
        float v = acc[mf][nf][r]*sc.w
                + sc.x*bv[nf][0] + sc.y*bv[nf][1] + sc.z*bv[nf][2] + sc.w*bv[nf][3];
        C[(size_t)gm*FF1 + gn] = (_Float16)v;
      }
    }
  }
}

// ---------------- GEMM2: out = sum_e s_e*(ctx @ W2_e) + bias ----------------
// 128x128 tile, BK=64, 8 waves (2M x 4N), dbuf, counted vmcnt(4), 2-phase
// compute with kk1-reads hoisted pre-barrier. Per-expert acc split.
#define G2_BK 64
#define G2_ABUF (128*G2_BK)
#define G2_BUFSZ (2*G2_ABUF)         // A+B per buffer = 32 KiB

__global__ __launch_bounds__(512) void gemm2_kernel(
    const _Float16* __restrict__ CTX, const _Float16* __restrict__ BT,
    const float* __restrict__ score, const float* __restrict__ bias,
    float* __restrict__ Cout)
{
  __shared__ _Float16 smem[2*G2_BUFSZ];   // 64 KiB
  int tid = threadIdx.x;
  int lane = tid & 63, wid = tid >> 6;
  int q = lane & 15, g = lane >> 4;
  int wr = wid >> 2, wc = wid & 3;     // 2M x 4N
  int xo = (q & 7) << 3;
  int bid = blockIdx.x;
  int xcd = bid >> 5, idx = bid & 31;
  int m0 = (xcd*4 + (idx >> 3)) * 128;
  int n0 = (idx & 7) * 128;

  int arow[4], brow[2];
  #pragma unroll
  for (int mf = 0; mf < 4; ++mf) arow[mf] = (wr*64 + mf*16 + q)*64;
  #pragma unroll
  for (int nf = 0; nf < 2; ++nf) brow[nf] = G2_ABUF + (wc*32 + nf*16 + q)*64;
  int soff[2] = { (g*8) ^ xo, (32 + g*8) ^ xo };

  auto stage = [&](int t, int buf){
    const int d0 = (t & 15) * G2_BK;
    const int k0 = t * G2_BK;
    _Float16* sA = smem + buf*G2_BUFSZ;
    _Float16* sB = sA + G2_ABUF;
    #pragma unroll
    for (int ld = 0; ld < 2; ++ld){
      int c = ld*512 + tid;
      int row = c >> 3;
      int seg = (c & 7) ^ (row & 7);
      GLOAD_LDS16(CTX + (size_t)(m0 + row)*DD + d0 + seg*8,
                  sA + (ld*512 + wid*64)*8);
    }
    #pragma unroll
    for (int ld = 0; ld < 2; ++ld){
      int c = ld*512 + tid;
      int row = c >> 3;
      int seg = (c & 7) ^ (row & 7);
      GLOAD_LDS16(BT + (size_t)(n0 + row)*KK2 + k0 + seg*8,
                  sB + (ld*512 + wid*64)*8);
    }
  };

  f32x4 accp[4][2] = {}, acco[4][2] = {};

  auto merge = [&](int e){
    #pragma unroll
    for (int m = 0; m < 4; ++m)
      #pragma unroll
      for (int r = 0; r < 4; ++r){
        int gm = m0 + wr*64 + m*16 + g*4 + r;
        float s = score[(size_t)gm*4 + e];
        #pragma unroll
        for (int n = 0; n < 2; ++n){
          acco[m][n][r] += s*accp[m][n][r];
          accp[m][n][r] = 0.f;
        }
      }
  };

  half8 af[4][2], bfr[2][2];
  auto reads = [&](const _Float16* base, int k){
    #pragma unroll
    for (int m = 0; m < 4; ++m)
      af[m][k] = *(const half8*)(base + arow[m] + soff[k]);
    #pragma unroll
    for (int n = 0; n < 2; ++n)
      bfr[n][k] = *(const half8*)(base + brow[n] + soff[k]);
  };
  auto mfmas = [&](int k){
    __builtin_amdgcn_s_setprio(1);
    #pragma unroll
    for (int m = 0; m < 4; ++m)
      #pragma unroll
      for (int n = 0; n < 2; ++n)
        accp[m][n] = mfma16(af[m][k], bfr[n][k], accp[m][n]);
    __builtin_amdgcn_s_setprio(0);
  };

  stage(0, 0);
  for (int t = 0; t < KK2/G2_BK - 1; ++t){
    const _Float16* base = smem + (t & 1)*G2_BUFSZ;
    stage(t+1, (t+1)&1);
    asm volatile("s_waitcnt vmcnt(4)" ::: "memory");  // tile t landed
    SBAR();
    reads(base, 0);
    mfmas(0);
    reads(base, 1);            // hoisted pre-barrier
    SBAR();                    // reads of buf(t) all issued -> restage safe next iter
    mfmas(1);
    if ((t & 15) == 15) merge(t >> 4);                // expert boundary
  }
  {
    const _Float16* base = smem + ((KK2/G2_BK - 1) & 1)*G2_BUFSZ;
    asm volatile("s_waitcnt vmcnt(0)" ::: "memory");
    SBAR();
    reads(base, 0); reads(base, 1);
    mfmas(0); mfmas(1);
    merge(3);
  }

  #pragma unroll
  for (int m = 0; m < 4; ++m){
    #pragma unroll
    for (int r = 0; r < 4; ++r){
      int gm = m0 + wr*64 + m*16 + g*4 + r;
      float4 sc = *(const float4*)(score + gm*4);
      #pragma unroll
      for (int n = 0; n < 2; ++n){
        int gn = n0 + wc*32 + n*16 + q;
        float v = acco[m][n][r]
                + sc.x*bias[gn] + sc.y*bias[DD+gn]
                + sc.z*bias[2*DD+gn] + sc.w*bias[3*DD+gn];
        Cout[(size_t)gm*DD + gn] = v;
      }
    }
  }
}

// ---------------- kernel 4: causal flash attention, QBLK=128, 8 waves -------
__global__ __launch_bounds__(512) void attn_kernel(
    const _Float16* __restrict__ qkv, _Float16* __restrict__ ctx)
{
  __shared__ _Float16 lsK[2][64*64];   // [key][hd], swizzled
  __shared__ _Float16 lsV[2][64*64];   // [hd][key], swizzled (transposed)
  __shared__ _Float16 lsP[8][16*64];   // per-wave P [qrow][key], swizzled
  int id = blockIdx.x;                 // 0..511
  int p = id >> 1, parity = id & 1;
  int bh = p & 63;
  int qtp = p >> 6;                    // 0..3
  int qt = parity ? qtp : 7 - qtp;     // pair (7-qtp, qtp): tiles sum = 18
  int b = bh >> 4, h = bh & 15;
  int tid = threadIdx.x, lane = tid & 63, wid = tid >> 6;   // wid 0..7
  int q = lane & 15, g = lane >> 4;
  int xo = (q & 7) << 3;
  int qrow0 = qt*128 + wid*16;

  half8 qf[2];
  #pragma unroll
  for (int kk = 0; kk < 2; ++kk)
    qf[kk] = *(const half8*)(qkv + ((size_t)b*SS + qrow0 + q)*FF1 + h*HDD + kk*32 + g*8);

  auto issueK = [&](int kt, int buf){
    size_t kvrow = (size_t)b*SS + kt*64;
    int row = tid >> 3, seg = (tid & 7) ^ (row & 7);
    GLOAD_LDS16(qkv + (kvrow + row)*FF1 + DD + h*HDD + seg*8,
                lsK[buf] + (size_t)(wid*64)*8);
  };
  auto issueV = [&](int kt, half8& vr){
    size_t kvrow = (size_t)b*SS + kt*64;
    vr = *(const half8*)(qkv + (kvrow + lane)*FF1 + 2*DD + h*HDD + wid*8);
  };
  auto writeV = [&](half8 vr, int buf){
    #pragma unroll
    for (int j = 0; j < 8; ++j){
      int hd = wid*8 + j;
      lsV[buf][hd*64 + (lane ^ ((hd & 7) << 3))] = vr[j];
    }
  };

  f32x4 o[4] = {};
  float mrow = -1e30f, lsum = 0.f;     // stats for qrow = q (log2 domain)
  const float SC2 = 0.18033688011112042f;  // log2(e)/8
  int qglob = qrow0 + q;
  int ktmax = 2*qt + 1;

  half8 vr;
  issueK(0, 0);
  issueV(0, vr);

  for (int kt = 0; kt <= ktmax; ++kt){
    int cur = kt & 1, nxt = cur ^ 1;
    int tn = (kt < ktmax) ? kt+1 : ktmax;
    bool active = (kt*64 <= qrow0 + 15);
    asm volatile("s_waitcnt vmcnt(1)" ::: "memory");
    SBAR();

    f32x4 st[4] = {};
    if (active){
      __builtin_amdgcn_s_setprio(1);
      #pragma unroll
      for (int i = 0; i < 4; ++i){
        #pragma unroll
        for (int kk = 0; kk < 2; ++kk){
          half8 kf = *(const half8*)(lsK[cur] + (i*16 + q)*64 + ((kk*32 + g*8) ^ xo));
          st[i] = mfma16(kf, qf[kk], st[i]);
        }
      }
      __builtin_amdgcn_s_setprio(0);
    }
    issueK(tn, nxt);
    asm volatile("s_waitcnt vmcnt(1)" ::: "memory");
    writeV(vr, cur);

    _Float16 pb[16];
    bool resc = false;
    float psum = 0.f;
    if (active){
      float pvv[16]; float tm = -1e30f;
      if (kt*64 + 63 > qrow0){
        #pragma unroll
        for (int i = 0; i < 4; ++i)
          #pragma unroll
          for (int r = 0; r < 4; ++r){
            int kglob = kt*64 + i*16 + g*4 + r;
            float sv = (kglob <= qglob) ? st[i][r]*SC2 : -1e30f;
            pvv[i*4+r] = sv; tm = fmaxf(tm, sv);
          }
      } else {
        #pragma unroll
        for (int i = 0; i < 4; ++i)
          #pragma unroll
          for (int r = 0; r < 4; ++r){
            float sv = st[i][r]*SC2;
            pvv[i*4+r] = sv; tm = fmaxf(tm, sv);
          }
      }
      tm = fmaxf(tm, __shfl_xor(tm, 16, 64));
      tm = fmaxf(tm, __shfl_xor(tm, 32, 64));
      resc = !__all(tm <= mrow);
      float mnew = resc ? fmaxf(mrow, tm) : mrow;
      #pragma unroll
      for (int i = 0; i < 16; ++i){
        float p2 = exp2f(pvv[i] - mnew);
        psum += p2; pb[i] = (_Float16)p2;
      }
      if (resc){
        float alpha = exp2f(mrow - mnew);
        mrow = mnew;
        lsum = lsum*alpha + psum;
        float af4[4];
        #pragma unroll
        for (int r = 0; r < 4; ++r) af4[r] = __shfl(alpha, g*4 + r, 64);
        #pragma unroll
        for (int n = 0; n < 4; ++n)
          #pragma unroll
          for (int r = 0; r < 4; ++r) o[n][r] *= af4[r];
      } else {
        lsum += psum;
      }
    }
    issueV(tn, vr);

    asm volatile("s_waitcnt lgkmcnt(0)" ::: "memory");
    SBAR();

    if (active){
      #pragma unroll
      for (int i = 0; i < 4; ++i){
        half4 w4;
        w4[0]=pb[i*4+0]; w4[1]=pb[i*4+1]; w4[2]=pb[i*4+2]; w4[3]=pb[i*4+3];
        *(half4*)(&lsP[wid][q*64 + ((i*16 + g*4) ^ xo)]) = w4;
      }
      __builtin_amdgcn_s_setprio(1);
      #pragma unroll
      for (int kk = 0; kk < 2; ++kk){
        half8 pf = *(const half8*)(&lsP[wid][q*64 + ((kk*32 + g*8) ^ xo)]);
        #pragma unroll
        for (int n = 0; n < 4; ++n){
          half8 vf = *(const half8*)(&lsV[cur][(n*16 + q)*64 + ((kk*32 + g*8) ^ xo)]);
          o[n] = mfma16(pf, vf, o[n]);
        }
      }
      __builtin_amdgcn_s_setprio(0);
    }
  }
  float lt = lsum + __shfl_xor(lsum, 16, 64);
  lt = lt + __shfl_xor(lt, 32, 64);
  float rinv = 1.f / lt;
  #pragma unroll
  for (int r = 0; r < 4; ++r){
    float ri = __shfl(rinv, g*4 + r, 64);
    int qg = qt*128 + wid*16 + g*4 + r;
    _Float16* obase = ctx + ((size_t)b*SS + qg)*DD + h*HDD;
    #pragma unroll
    for (int n = 0; n < 4; ++n)
      obase[n*16 + q] = (_Float16)(o[n][r] * ri);
  }
}

// ---------------------------------------------------------------------------
extern "C" void kernel_launch(void* const* d_in, const int* in_sizes, int n_in,
                              void* d_out, int out_size, void* d_ws, size_t ws_size,
                              hipStream_t stream)
{
  const float* x      = (const float*)d_in[0];
  const float* Wr     = (const float*)d_in[1];
  const float* br     = (const float*)d_in[2];
  const float* ln_g   = (const float*)d_in[3];
  const float* ln_b   = (const float*)d_in[4];
  const float* W_attn = (const float*)d_in[5];
  const float* b_attn = (const float*)d_in[6];
  const float* W_proj = (const float*)d_in[7];
  const float* b_proj = (const float*)d_in[8];
  (void)in_sizes; (void)n_in; (void)out_size; (void)ws_size;

  char* ws = (char*)d_ws;
  size_t off = 0;
  auto alloc = [&](size_t bytes) -> void* {
    void* p = ws + off; off += (bytes + 255) & ~(size_t)255; return p;
  };
  _Float16* W1gT  = (_Float16*)alloc((size_t)FF1*KK2*2);   // 25.2 MB (g folded)
  _Float16* W2T   = (_Float16*)alloc((size_t)DD*KK2*2);    //  8.4 MB
  float*    score = (float*)   alloc((size_t)NN*4*4);      // 64 KB
  float*    ratio = (float*)   alloc((size_t)NN*4*4);      // 64 KB
  _Float16* xn16  = (_Float16*)alloc((size_t)NN*DD*2);     //  8.4 MB
  _Float16* qkv   = (_Float16*)alloc((size_t)NN*FF1*2);    // 25.2 MB
  _Float16* ctx   = (_Float16*)alloc((size_t)NN*DD*2);     //  8.4 MB
  float*    part  = (float*)   alloc((size_t)(KK2/64)*FF1*4); // 786 KB
  float*    BB1   = (float*)   alloc((size_t)EE*FF1*4);    // 48 KB

  hipLaunchKernelGGL(prep_fused_kernel, dim3(8192), dim3(256), 0, stream,
                     W_attn, W1gT, W_proj, W2T, ln_g, ln_b, part,
                     x, Wr, br, score, ratio, xn16);
  hipLaunchKernelGGL(bb1_kernel, dim3(EE*FF1/256), dim3(256), 0, stream,
                     b_attn, part, BB1);
  hipLaunchKernelGGL(gemm1_kernel, dim3(512), dim3(512), 0, stream,
                     xn16, W1gT, score, ratio, BB1, qkv);
  hipLaunchKernelGGL(attn_kernel, dim3(512), dim3(512), 0, stream,
                     qkv, ctx);
  hipLaunchKernelGGL(gemm2_kernel, dim3(256), dim3(512), 0, stream,
                     ctx, W2T, score, b_proj, (float*)d_out);
}

// Round 15
// 201.752 us; speedup vs baseline: 1.0225x; 1.0225x over previous
//
#include <hip/hip_runtime.h>
#include <stdint.h>

#define NB 4
#define SS 1024
#define DD 1024
#define EE 4
#define HH 16
#define HDD 64
#define NN (NB*SS)      // 4096 tokens
#define KK2 (EE*DD)     // 4096 expanded K
#define FF1 (3*DD)      // 3072

typedef __attribute__((ext_vector_type(4))) float f32x4;
typedef __attribute__((ext_vector_type(8))) _Float16 half8;
typedef __attribute__((ext_vector_type(4))) _Float16 half4;

static __device__ __forceinline__ f32x4 mfma16(half8 a, half8 b, f32x4 c){
  return __builtin_amdgcn_mfma_f32_16x16x32_f16(a, b, c, 0, 0, 0);
}

// async global->LDS, 16B per lane; LDS dest = wave-uniform base + lane*16
#define GLOAD_LDS16(gp, lp) __builtin_amdgcn_global_load_lds( \
    (const unsigned int __attribute__((address_space(1)))*)(uintptr_t)(gp), \
    (unsigned int __attribute__((address_space(3)))*)(uintptr_t)(lp), 16, 0, 0)

#define SBAR() do { asm volatile("" ::: "memory"); \
                    __builtin_amdgcn_s_barrier(); \
                    asm volatile("" ::: "memory"); } while(0)
#define VMC(n) asm volatile("s_waitcnt vmcnt(" #n ")" ::: "memory")

// ---------------- fused prologue: W transposes + router/LN prep -------------
__device__ __forceinline__ void prep_body(
    const float* __restrict__ x, const float* __restrict__ Wr,
    const float* __restrict__ br, float* __restrict__ score,
    float* __restrict__ ratios, _Float16* __restrict__ xnb,
    int n, float (*red)[6])
{
  int tid = threadIdx.x;
  float4 xv = ((const float4*)(x + (size_t)n*DD))[tid];   // d = tid*4..+3
  float xa[4] = {xv.x, xv.y, xv.z, xv.w};
  float vals[6];
  vals[0] = xa[0]+xa[1]+xa[2]+xa[3];
  vals[1] = xa[0]*xa[0]+xa[1]*xa[1]+xa[2]*xa[2]+xa[3]*xa[3];
  vals[2] = vals[3] = vals[4] = vals[5] = 0.f;
  #pragma unroll
  for (int j = 0; j < 4; ++j){
    float4 w = ((const float4*)Wr)[tid*4 + j];
    vals[2] += xa[j]*w.x; vals[3] += xa[j]*w.y;
    vals[4] += xa[j]*w.z; vals[5] += xa[j]*w.w;
  }
  #pragma unroll
  for (int off = 32; off >= 1; off >>= 1)
    #pragma unroll
    for (int i = 0; i < 6; ++i)
      vals[i] += __shfl_xor(vals[i], off, 64);
  int wid = tid >> 6;
  if ((tid & 63) == 0){
    #pragma unroll
    for (int i = 0; i < 6; ++i) red[wid][i] = vals[i];
  }
  __syncthreads();
  float tot[6];
  #pragma unroll
  for (int i = 0; i < 6; ++i)
    tot[i] = red[0][i] + red[1][i] + red[2][i] + red[3][i];

  float mu   = tot[0] * (1.f/DD);
  float var  = tot[1] * (1.f/DD) - mu*mu;
  float rsig = rsqrtf(var + 1e-5f);
  float lg[4];
  #pragma unroll
  for (int e = 0; e < 4; ++e) lg[e] = tot[2+e] + br[e];
  float mx = fmaxf(fmaxf(lg[0], lg[1]), fmaxf(lg[2], lg[3]));
  float ex[4], esum = 0.f;
  #pragma unroll
  for (int e = 0; e < 4; ++e){ ex[e] = __expf(lg[e] - mx); esum += ex[e]; }
  if (tid < 4){
    score[n*4 + tid] = ex[tid] / esum;
    // expert-inner telescoping: r0 = s0; r_e = s_e/s_{e-1}
    ratios[n*4 + tid] = (tid == 0) ? (ex[0] / esum) : (ex[tid] / ex[tid-1]);
  }

  half4 o;
  #pragma unroll
  for (int j = 0; j < 4; ++j) o[j] = (_Float16)((xa[j] - mu) * rsig);
  *(half4*)(xnb + (size_t)n*DD + tid*4) = o;
}

template<bool AFFINE>
__device__ __forceinline__ void transpose_body(
    const float* __restrict__ W, _Float16* __restrict__ WT, int K, int F,
    const float* __restrict__ gvec, const float* __restrict__ bvec,
    float* __restrict__ part, int k0, int f0,
    float (*t)[65], float (*red2)[64])
{
  int tid = threadIdx.x;
  int r = tid >> 4, c4 = (tid & 15) * 4;
  float pf[4] = {0.f, 0.f, 0.f, 0.f};
  #pragma unroll
  for (int i = 0; i < 4; ++i){
    int k = k0 + i*16 + r;
    float4 v = *(const float4*)(W + (size_t)k*F + f0 + c4);
    if constexpr (AFFINE){
      float bk = bvec[k];
      pf[0] += bk*v.x; pf[1] += bk*v.y; pf[2] += bk*v.z; pf[3] += bk*v.w;
      float gk = gvec[k];
      v.x *= gk; v.y *= gk; v.z *= gk; v.w *= gk;
    }
    t[i*16 + r][c4+0] = v.x; t[i*16 + r][c4+1] = v.y;
    t[i*16 + r][c4+2] = v.z; t[i*16 + r][c4+3] = v.w;
  }
  if constexpr (AFFINE){
    #pragma unroll
    for (int j = 0; j < 4; ++j) red2[r][c4+j] = pf[j];
  }
  __syncthreads();
  int f = tid >> 2, seg = tid & 3;
  half8 o0, o1;
  #pragma unroll
  for (int j = 0; j < 8; ++j){
    o0[j] = (_Float16)t[seg*16 + j][f];
    o1[j] = (_Float16)t[seg*16 + 8 + j][f];
  }
  _Float16* dst = WT + (size_t)(f0 + f)*K + k0 + seg*16;
  *(half8*)dst = o0;
  *(half8*)(dst + 8) = o1;
  if constexpr (AFFINE){
    if (tid < 64){
      float s = 0.f;
      #pragma unroll
      for (int rr = 0; rr < 16; ++rr) s += red2[rr][tid];
      part[(size_t)(k0/64) * F + f0 + tid] = s;
    }
  }
}

__global__ __launch_bounds__(256) void prep_fused_kernel(
    const float* __restrict__ W1, _Float16* __restrict__ W1T,
    const float* __restrict__ W2, _Float16* __restrict__ W2T,
    const float* __restrict__ gvec, const float* __restrict__ bvec,
    float* __restrict__ part,
    const float* __restrict__ x, const float* __restrict__ Wr,
    const float* __restrict__ br, float* __restrict__ score,
    float* __restrict__ ratios, _Float16* __restrict__ xnb)
{
  __shared__ float t[64][65];
  __shared__ float red2[16][64];
  __shared__ float red[4][6];
  int id = blockIdx.x;
  if (id & 1){
    prep_body(x, Wr, br, score, ratios, xnb, id >> 1, red);
  } else {
    int tr = id >> 1;
    int k0 = (tr & 63) * 64;
    int y  = tr >> 6;
    if (y < FF1/64)
      transpose_body<true >(W1, W1T, KK2, FF1, gvec, bvec, part, k0, y*64, t, red2);
    else
      transpose_body<false>(W2, W2T, KK2, DD, nullptr, nullptr, nullptr,
                            k0, (y - FF1/64)*64, t, red2);
  }
}

// ---------------- BB1[e,f] = b_attn[e,f] + sum_i part[e*16+i, f] ------------
__global__ __launch_bounds__(256) void bb1_kernel(
    const float* __restrict__ b_attn, const float* __restrict__ part,
    float* __restrict__ BB1)
{
  int idx = blockIdx.x*256 + threadIdx.x;   // e*FF1 + f
  int e = idx / FF1, f = idx - e*FF1;
  float s = b_attn[idx];
  #pragma unroll
  for (int i = 0; i < 16; ++i)
    s += part[(size_t)(e*16 + i)*FF1 + f];
  BB1[idx] = s;
}

// ---------------- GEMM1 (expert-inner): qkv = sum_e s_e*(xn @ W1g_e) + b ----
// [R13-best: 93.5us, FETCH 45.7MB] 256x192 tile, 8 waves (4M x 2N). Per
// d0-tile A-frags in regs once, 4 expert phases; f16 telescoping on A-frags.
// A dbuf 64 KiB; B triple 72 KiB; vmcnt {3,3,3,7}, 1 barrier/phase.
#define G1_BM 256
#define G1_BN 192
#define G1_BK 64
#define G1_NT 16                      // d0 tiles
#define G1_ABUF (G1_BM*G1_BK)         // 16384 f16 = 32 KiB
#define G1_BBUF (G1_BN*G1_BK)         // 12288 f16 = 24 KiB

__global__ __launch_bounds__(512, 2) void gemm1_kernel(
    const _Float16* __restrict__ XN, const _Float16* __restrict__ BT,
    const float* __restrict__ score, const float* __restrict__ ratios,
    const float* __restrict__ bias, _Float16* __restrict__ C)
{
  __shared__ _Float16 smA[2*G1_ABUF];   // 64 KiB
  __shared__ _Float16 smB[3*G1_BBUF];   // 72 KiB
  int tid = threadIdx.x;
  int lane = tid & 63, wid = tid >> 6;
  int q = lane & 15, g = lane >> 4;
  int wr = wid >> 1, wc = wid & 1;
  int xo = (q & 7) << 3;
  int bid = blockIdx.x;
  int xcd = bid & 7, li = bid >> 3;
  int m0 = (li >> 1) * G1_BM;
  int n0 = (xcd*2 + (li & 1)) * G1_BN;

  int arow[4], brow[6];
  #pragma unroll
  for (int mf = 0; mf < 4; ++mf) arow[mf] = (wr*64 + mf*16 + q)*64;
  #pragma unroll
  for (int nf = 0; nf < 6; ++nf) brow[nf] = (wc*96 + nf*16 + q)*64;
  int soff[2] = { (g*8) ^ xo, (32 + g*8) ^ xo };

  _Float16 rf[4][4];
  #pragma unroll
  for (int mf = 0; mf < 4; ++mf){
    float4 rr = *(const float4*)(ratios + (size_t)(m0 + wr*64 + mf*16 + q)*4);
    rf[mf][0] = (_Float16)rr.x; rf[mf][1] = (_Float16)rr.y;
    rf[mf][2] = (_Float16)rr.z; rf[mf][3] = (_Float16)rr.w;
  }

  auto stageA = [&](int t){                 // 4 loads, buf t&1
    _Float16* sA = smA + (t & 1)*G1_ABUF;
    const int d0 = t * G1_BK;
    #pragma unroll
    for (int ld = 0; ld < 4; ++ld){
      int c = ld*512 + tid;
      int row = c >> 3;
      int seg = (c & 7) ^ (row & 7);        // inverse-swizzled global source
      GLOAD_LDS16(XN + (size_t)(m0 + row)*DD + d0 + seg*8,
                  sA + (ld*512 + wid*64)*8);
    }
  };
  auto stageB = [&](int gec){               // 3 loads, buf gec%3; gec = t*4+e
    const int k0 = (gec & 3)*DD + (gec >> 2)*G1_BK;
    _Float16* sB = smB + (gec % 3)*G1_BBUF;
    #pragma unroll
    for (int ld = 0; ld < 3; ++ld){
      int c = ld*512 + tid;
      int row = c >> 3;
      int seg = (c & 7) ^ (row & 7);
      GLOAD_LDS16(BT + (size_t)(n0 + row)*KK2 + k0 + seg*8,
                  sB + (ld*512 + wid*64)*8);
    }
  };

  f32x4 acc[4][6] = {};
  half8 af[4][2];                           // A frags, live across 4 phases

  auto phase = [&](const _Float16* Ab, const _Float16* Bb,
                   _Float16 s0, _Float16 s1, _Float16 s2, _Float16 s3,
                   bool readAF){
    if (readAF){
      #pragma unroll
      for (int m = 0; m < 4; ++m)
        #pragma unroll
        for (int k = 0; k < 2; ++k)
          af[m][k] = *(const half8*)(Ab + arow[m] + soff[k]);
    }
    #pragma unroll
    for (int k = 0; k < 2; ++k)
      #pragma unroll
      for (int j = 0; j < 8; ++j){
        af[0][k][j] *= s0; af[1][k][j] *= s1;
        af[2][k][j] *= s2; af[3][k][j] *= s3;
      }
    half8 bf[3][2];
    #pragma unroll
    for (int n = 0; n < 3; ++n)
      #pragma unroll
      for (int k = 0; k < 2; ++k)
        bf[n][k] = *(const half8*)(Bb + brow[n] + soff[k]);
    __builtin_amdgcn_s_setprio(1);
    #pragma unroll
    for (int k = 0; k < 2; ++k)
      #pragma unroll
      for (int m = 0; m < 4; ++m)
        #pragma unroll
        for (int n = 0; n < 3; ++n)
          acc[m][n] = mfma16(af[m][k], bf[n][k], acc[m][n]);
    __builtin_amdgcn_s_setprio(0);
    #pragma unroll
    for (int n = 0; n < 3; ++n)
      #pragma unroll
      for (int k = 0; k < 2; ++k)
        bf[n][k] = *(const half8*)(Bb + brow[3+n] + soff[k]);
    __builtin_amdgcn_s_setprio(1);
    #pragma unroll
    for (int k = 0; k < 2; ++k)
      #pragma unroll
      for (int m = 0; m < 4; ++m)
        #pragma unroll
        for (int n = 0; n < 3; ++n)
          acc[m][3+n] = mfma16(af[m][k], bf[n][k], acc[m][3+n]);
    __builtin_amdgcn_s_setprio(0);
  };

  stageA(0); stageB(0); stageB(1);

  #pragma unroll 1
  for (int t = 0; t < G1_NT-1; ++t){
    const _Float16* Ab = smA + (t & 1)*G1_ABUF;
    int g4 = t*4;
    VMC(3); SBAR();
    stageB(g4+2);
    phase(Ab, smB + (g4 % 3)*G1_BBUF, rf[0][0], rf[1][0], rf[2][0], rf[3][0], true);
    VMC(3); SBAR();
    stageB(g4+3);
    phase(Ab, smB + ((g4+1) % 3)*G1_BBUF, rf[0][1], rf[1][1], rf[2][1], rf[3][1], false);
    VMC(3); SBAR();
    stageB(g4+4); stageA(t+1);
    phase(Ab, smB + ((g4+2) % 3)*G1_BBUF, rf[0][2], rf[1][2], rf[2][2], rf[3][2], false);
    VMC(7); SBAR();
    stageB(g4+5);
    phase(Ab, smB + ((g4+3) % 3)*G1_BBUF, rf[0][3], rf[1][3], rf[2][3], rf[3][3], false);
  }
  {
    const _Float16* Ab = smA + ((G1_NT-1) & 1)*G1_ABUF;
    VMC(3); SBAR();
    stageB(62);
    phase(Ab, smB + (60 % 3)*G1_BBUF, rf[0][0], rf[1][0], rf[2][0], rf[3][0], true);
    VMC(3); SBAR();
    stageB(63);
    phase(Ab, smB + (61 % 3)*G1_BBUF, rf[0][1], rf[1][1], rf[2][1], rf[3][1], false);
    VMC(3); SBAR();
    phase(Ab, smB + (62 % 3)*G1_BBUF, rf[0][2], rf[1][2], rf[2][2], rf[3][2], false);
    VMC(0); SBAR();
    phase(Ab, smB + (63 % 3)*G1_BBUF, rf[0][3], rf[1][3], rf[2][3], rf[3][3], false);
  }

  // epilogue: acc includes all s_e; add sum_e score*BB1, f16 store
  float bv[6][4];
  #pragma unroll
  for (int nf = 0; nf < 6; ++nf){
    int gn = n0 + wc*96 + nf*16 + q;
    #pragma unroll
    for (int e = 0; e < 4; ++e) bv[nf][e] = bias[e*FF1 + gn];
  }
  #pragma unroll
  for (int mf = 0; mf < 4; ++mf){
    #pragma unroll
    for (int r = 0; r < 4; ++r){
      int gm = m0 + wr*64 + mf*16 + g*4 + r;
      float4 sc = *(const float4*)(score + gm*4);
      #pragma unroll
      for (int nf = 0; nf < 6; ++nf){
        int gn = n0 + wc*96 + nf*16 + q;
        float v = acc[mf][nf][r]
                + sc.x*bv[nf][0] + sc.y*bv[nf][1] + sc.z*bv[nf][2] + sc.w*bv[nf][3];
        C[(size_t)gm*FF1 + gn] = (_Float16)v;
      }
    }
  }
}

// ---------------- GEMM2 (expert-inner): out = sum_e s_e*(ctx @ W2_e) + b ----
// 128x128 tile, 8 waves (2M x 4N). Same expert-inner pattern: per d0-tile
// A-frags (ctx) in regs once, 4 expert phases staging only B[e]; f16
// telescoping on A-frags. A dbuf 32 KiB + B triple 48 KiB = 80 KiB.
// vmcnt {2,2,2,4}, 1 barrier/phase; tail {2,2,2,0}.
#define G2_BK 64
#define G2_NT 16
#define G2_ABUF (128*G2_BK)           // 8192 f16 = 16 KiB
#define G2_BBUF (128*G2_BK)           // 16 KiB

__global__ __launch_bounds__(512, 4) void gemm2_kernel(
    const _Float16* __restrict__ CTX, const _Float16* __restrict__ BT,
    const float* __restrict__ score, const float* __restrict__ ratios,
    const float* __restrict__ bias, float* __restrict__ Cout)
{
  __shared__ _Float16 smA[2*G2_ABUF];   // 32 KiB
  __shared__ _Float16 smB[3*G2_BBUF];   // 48 KiB
  int tid = threadIdx.x;
  int lane = tid & 63, wid = tid >> 6;
  int q = lane & 15, g = lane >> 4;
  int wr = wid >> 2, wc = wid & 3;      // 2M x 4N
  int xo = (q & 7) << 3;
  int bid = blockIdx.x;
  int xcd = bid >> 5, idx = bid & 31;
  int m0 = (xcd*4 + (idx >> 3)) * 128;
  int n0 = (idx & 7) * 128;

  int arow[4], brow[2];
  #pragma unroll
  for (int mf = 0; mf < 4; ++mf) arow[mf] = (wr*64 + mf*16 + q)*64;
  #pragma unroll
  for (int nf = 0; nf < 2; ++nf) brow[nf] = (wc*32 + nf*16 + q)*64;
  int soff[2] = { (g*8) ^ xo, (32 + g*8) ^ xo };

  _Float16 rf[4][4];
  #pragma unroll
  for (int mf = 0; mf < 4; ++mf){
    float4 rr = *(const float4*)(ratios + (size_t)(m0 + wr*64 + mf*16 + q)*4);
    rf[mf][0] = (_Float16)rr.x; rf[mf][1] = (_Float16)rr.y;
    rf[mf][2] = (_Float16)rr.z; rf[mf][3] = (_Float16)rr.w;
  }

  auto stageA = [&](int t){                 // 2 loads, buf t&1
    _Float16* sA = smA + (t & 1)*G2_ABUF;
    const int d0 = t * G2_BK;
    #pragma unroll
    for (int ld = 0; ld < 2; ++ld){
      int c = ld*512 + tid;
      int row = c >> 3;
      int seg = (c & 7) ^ (row & 7);
      GLOAD_LDS16(CTX + (size_t)(m0 + row)*DD + d0 + seg*8,
                  sA + (ld*512 + wid*64)*8);
    }
  };
  auto stageB = [&](int gec){               // 2 loads, buf gec%3; gec = t*4+e
    const int k0 = (gec & 3)*DD + (gec >> 2)*G2_BK;
    _Float16* sB = smB + (gec % 3)*G2_BBUF;
    #pragma unroll
    for (int ld = 0; ld < 2; ++ld){
      int c = ld*512 + tid;
      int row = c >> 3;
      int seg = (c & 7) ^ (row & 7);
      GLOAD_LDS16(BT + (size_t)(n0 + row)*KK2 + k0 + seg*8,
                  sB + (ld*512 + wid*64)*8);
    }
  };

  f32x4 acc[4][2] = {};
  half8 af[4][2];

  auto phase = [&](const _Float16* Ab, const _Float16* Bb,
                   _Float16 s0, _Float16 s1, _Float16 s2, _Float16 s3,
                   bool readAF){
    if (readAF){
      #pragma unroll
      for (int m = 0; m < 4; ++m)
        #pragma unroll
        for (int k = 0; k < 2; ++k)
          af[m][k] = *(const half8*)(Ab + arow[m] + soff[k]);
    }
    #pragma unroll
    for (int k = 0; k < 2; ++k)
      #pragma unroll
      for (int j = 0; j < 8; ++j){
        af[0][k][j] *= s0; af[1][k][j] *= s1;
        af[2][k][j] *= s2; af[3][k][j] *= s3;
      }
    half8 bf[2][2];
    #pragma unroll
    for (int n = 0; n < 2; ++n)
      #pragma unroll
      for (int k = 0; k < 2; ++k)
        bf[n][k] = *(const half8*)(Bb + brow[n] + soff[k]);
    __builtin_amdgcn_s_setprio(1);
    #pragma unroll
    for (int k = 0; k < 2; ++k)
      #pragma unroll
      for (int m = 0; m < 4; ++m)
        #pragma unroll
        for (int n = 0; n < 2; ++n)
          acc[m][n] = mfma16(af[m][k], bf[n][k], acc[m][n]);
    __builtin_amdgcn_s_setprio(0);
  };

  stageA(0); stageB(0); stageB(1);          // 6 loads in flight

  #pragma unroll 1
  for (int t = 0; t < G2_NT-1; ++t){
    const _Float16* Ab = smA + (t & 1)*G2_ABUF;
    int g4 = t*4;
    VMC(2); SBAR();
    stageB(g4+2);
    phase(Ab, smB + (g4 % 3)*G2_BBUF, rf[0][0], rf[1][0], rf[2][0], rf[3][0], true);
    VMC(2); SBAR();
    stageB(g4+3);
    phase(Ab, smB + ((g4+1) % 3)*G2_BBUF, rf[0][1], rf[1][1], rf[2][1], rf[3][1], false);
    VMC(2); SBAR();
    stageB(g4+4); stageA(t+1);
    phase(Ab, smB + ((g4+2) % 3)*G2_BBUF, rf[0][2], rf[1][2], rf[2][2], rf[3][2], false);
    VMC(4); SBAR();
    stageB(g4+5);
    phase(Ab, smB + ((g4+3) % 3)*G2_BBUF, rf[0][3], rf[1][3], rf[2][3], rf[3][3], false);
  }
  {
    const _Float16* Ab = smA + ((G2_NT-1) & 1)*G2_ABUF;
    VMC(2); SBAR();
    stageB(62);
    phase(Ab, smB + (60 % 3)*G2_BBUF, rf[0][0], rf[1][0], rf[2][0], rf[3][0], true);
    VMC(2); SBAR();
    stageB(63);
    phase(Ab, smB + (61 % 3)*G2_BBUF, rf[0][1], rf[1][1], rf[2][1], rf[3][1], false);
    VMC(2); SBAR();
    phase(Ab, smB + (62 % 3)*G2_BBUF, rf[0][2], rf[1][2], rf[2][2], rf[3][2], false);
    VMC(0); SBAR();
    phase(Ab, smB + (63 % 3)*G2_BBUF, rf[0][3], rf[1][3], rf[2][3], rf[3][3], false);
  }

  // epilogue: acc includes all s_e; add sum_e score*b_proj, fp32 store
  #pragma unroll
  for (int m = 0; m < 4; ++m){
    #pragma unroll
    for (int r = 0; r < 4; ++r){
      int gm = m0 + wr*64 + m*16 + g*4 + r;
      float4 sc = *(const float4*)(score + gm*4);
      #pragma unroll
      for (int n = 0; n < 2; ++n){
        int gn = n0 + wc*32 + n*16 + q;
        float v = acc[m][n][r]
                + sc.x*bias[gn] + sc.y*bias[DD+gn]
                + sc.z*bias[2*DD+gn] + sc.w*bias[3*DD+gn];
        Cout[(size_t)gm*DD + gn] = v;
      }
    }
  }
}

// ---------------- kernel 4: causal flash attention, QBLK=128, 8 waves -------
__global__ __launch_bounds__(512) void attn_kernel(
    const _Float16* __restrict__ qkv, _Float16* __restrict__ ctx)
{
  __shared__ _Float16 lsK[2][64*64];   // [key][hd], swizzled
  __shared__ _Float16 lsV[2][64*64];   // [hd][key], swizzled (transposed)
  __shared__ _Float16 lsP[8][16*64];   // per-wave P [qrow][key], swizzled
  int id = blockIdx.x;                 // 0..511
  int p = id >> 1, parity = id & 1;
  int bh = p & 63;
  int qtp = p >> 6;                    // 0..3
  int qt = parity ? qtp : 7 - qtp;     // pair (7-qtp, qtp): tiles sum = 18
  int b = bh >> 4, h = bh & 15;
  int tid = threadIdx.x, lane = tid & 63, wid = tid >> 6;   // wid 0..7
  int q = lane & 15, g = lane >> 4;
  int xo = (q & 7) << 3;
  int qrow0 = qt*128 + wid*16;

  half8 qf[2];
  #pragma unroll
  for (int kk = 0; kk < 2; ++kk)
    qf[kk] = *(const half8*)(qkv + ((size_t)b*SS + qrow0 + q)*FF1 + h*HDD + kk*32 + g*8);

  auto issueK = [&](int kt, int buf){
    size_t kvrow = (size_t)b*SS + kt*64;
    int row = tid >> 3, seg = (tid & 7) ^ (row & 7);
    GLOAD_LDS16(qkv + (kvrow + row)*FF1 + DD + h*HDD + seg*8,
                lsK[buf] + (size_t)(wid*64)*8);
  };
  auto issueV = [&](int kt, half8& vr){
    size_t kvrow = (size_t)b*SS + kt*64;
    vr = *(const half8*)(qkv + (kvrow + lane)*FF1 + 2*DD + h*HDD + wid*8);
  };
  auto writeV = [&](half8 vr, int buf){
    #pragma unroll
    for (int j = 0; j < 8; ++j){
      int hd = wid*8 + j;
      lsV[buf][hd*64 + (lane ^ ((hd & 7) << 3))] = vr[j];
    }
  };

  f32x4 o[4] = {};
  float mrow = -1e30f, lsum = 0.f;     // stats for qrow = q (log2 domain)
  const float SC2 = 0.18033688011112042f;  // log2(e)/8
  int qglob = qrow0 + q;
  int ktmax = 2*qt + 1;

  half8 vr;
  issueK(0, 0);
  issueV(0, vr);

  for (int kt = 0; kt <= ktmax; ++kt){
    int cur = kt & 1, nxt = cur ^ 1;
    int tn = (kt < ktmax) ? kt+1 : ktmax;
    bool active = (kt*64 <= qrow0 + 15);
    asm volatile("s_waitcnt vmcnt(1)" ::: "memory");
    SBAR();

    f32x4 st[4] = {};
    if (active){
      __builtin_amdgcn_s_setprio(1);
      #pragma unroll
      for (int i = 0; i < 4; ++i){
        #pragma unroll
        for (int kk = 0; kk < 2; ++kk){
          half8 kf = *(const half8*)(lsK[cur] + (i*16 + q)*64 + ((kk*32 + g*8) ^ xo));
          st[i] = mfma16(kf, qf[kk], st[i]);
        }
      }
      __builtin_amdgcn_s_setprio(0);
    }
    issueK(tn, nxt);
    asm volatile("s_waitcnt vmcnt(1)" ::: "memory");
    writeV(vr, cur);

    _Float16 pb[16];
    bool resc = false;
    float psum = 0.f;
    if (active){
      float pvv[16]; float tm = -1e30f;
      if (kt*64 + 63 > qrow0){
        #pragma unroll
        for (int i = 0; i < 4; ++i)
          #pragma unroll
          for (int r = 0; r < 4; ++r){
            int kglob = kt*64 + i*16 + g*4 + r;
            float sv = (kglob <= qglob) ? st[i][r]*SC2 : -1e30f;
            pvv[i*4+r] = sv; tm = fmaxf(tm, sv);
          }
      } else {
        #pragma unroll
        for (int i = 0; i < 4; ++i)
          #pragma unroll
          for (int r = 0; r < 4; ++r){
            float sv = st[i][r]*SC2;
            pvv[i*4+r] = sv; tm = fmaxf(tm, sv);
          }
      }
      tm = fmaxf(tm, __shfl_xor(tm, 16, 64));
      tm = fmaxf(tm, __shfl_xor(tm, 32, 64));
      resc = !__all(tm <= mrow);
      float mnew = resc ? fmaxf(mrow, tm) : mrow;
      #pragma unroll
      for (int i = 0; i < 16; ++i){
        float p2 = exp2f(pvv[i] - mnew);
        psum += p2; pb[i] = (_Float16)p2;
      }
      if (resc){
        float alpha = exp2f(mrow - mnew);
        mrow = mnew;
        lsum = lsum*alpha + psum;
        float af4[4];
        #pragma unroll
        for (int r = 0; r < 4; ++r) af4[r] = __shfl(alpha, g*4 + r, 64);
        #pragma unroll
        for (int n = 0; n < 4; ++n)
          #pragma unroll
          for (int r = 0; r < 4; ++r) o[n][r] *= af4[r];
      } else {
        lsum += psum;
      }
    }
    issueV(tn, vr);

    asm volatile("s_waitcnt lgkmcnt(0)" ::: "memory");
    SBAR();

    if (active){
      #pragma unroll
      for (int i = 0; i < 4; ++i){
        half4 w4;
        w4[0]=pb[i*4+0]; w4[1]=pb[i*4+1]; w4[2]=pb[i*4+2]; w4[3]=pb[i*4+3];
        *(half4*)(&lsP[wid][q*64 + ((i*16 + g*4) ^ xo)]) = w4;
      }
      __builtin_amdgcn_s_setprio(1);
      #pragma unroll
      for (int kk = 0; kk < 2; ++kk){
        half8 pf = *(const half8*)(&lsP[wid][q*64 + ((kk*32 + g*8) ^ xo)]);
        #pragma unroll
        for (int n = 0; n < 4; ++n){
          half8 vf = *(const half8*)(&lsV[cur][(n*16 + q)*64 + ((kk*32 + g*8) ^ xo)]);
          o[n] = mfma16(pf, vf, o[n]);
        }
      }
      __builtin_amdgcn_s_setprio(0);
    }
  }
  float lt = lsum + __shfl_xor(lsum, 16, 64);
  lt = lt + __shfl_xor(lt, 32, 64);
  float rinv = 1.f / lt;
  #pragma unroll
  for (int r = 0; r < 4; ++r){
    float ri = __shfl(rinv, g*4 + r, 64);
    int qg = qt*128 + wid*16 + g*4 + r;
    _Float16* obase = ctx + ((size_t)b*SS + qg)*DD + h*HDD;
    #pragma unroll
    for (int n = 0; n < 4; ++n)
      obase[n*16 + q] = (_Float16)(o[n][r] * ri);
  }
}

// ---------------------------------------------------------------------------
extern "C" void kernel_launch(void* const* d_in, const int* in_sizes, int n_in,
                              void* d_out, int out_size, void* d_ws, size_t ws_size,
                              hipStream_t stream)
{
  const float* x      = (const float*)d_in[0];
  const float* Wr     = (const float*)d_in[1];
  const float* br     = (const float*)d_in[2];
  const float* ln_g   = (const float*)d_in[3];
  const float* ln_b   = (const float*)d_in[4];
  const float* W_attn = (const float*)d_in[5];
  const float* b_attn = (const float*)d_in[6];
  const float* W_proj = (const float*)d_in[7];
  const float* b_proj = (const float*)d_in[8];
  (void)in_sizes; (void)n_in; (void)out_size; (void)ws_size;

  char* ws = (char*)d_ws;
  size_t off = 0;
  auto alloc = [&](size_t bytes) -> void* {
    void* p = ws + off; off += (bytes + 255) & ~(size_t)255; return p;
  };
  _Float16* W1gT  = (_Float16*)alloc((size_t)FF1*KK2*2);   // 25.2 MB (g folded)
  _Float16* W2T   = (_Float16*)alloc((size_t)DD*KK2*2);    //  8.4 MB
  float*    score = (float*)   alloc((size_t)NN*4*4);      // 64 KB
  float*    ratio = (float*)   alloc((size_t)NN*4*4);      // 64 KB
  _Float16* xn16  = (_Float16*)alloc((size_t)NN*DD*2);     //  8.4 MB
  _Float16* qkv   = (_Float16*)alloc((size_t)NN*FF1*2);    // 25.2 MB
  _Float16* ctx   = (_Float16*)alloc((size_t)NN*DD*2);     //  8.4 MB
  float*    part  = (float*)   alloc((size_t)(KK2/64)*FF1*4); // 786 KB
  float*    BB1   = (float*)   alloc((size_t)EE*FF1*4);    // 48 KB

  hipLaunchKernelGGL(prep_fused_kernel, dim3(8192), dim3(256), 0, stream,
                     W_attn, W1gT, W_proj, W2T, ln_g, ln_b, part,
                     x, Wr, br, score, ratio, xn16);
  hipLaunchKernelGGL(bb1_kernel, dim3(EE*FF1/256), dim3(256), 0, stream,
                     b_attn, part, BB1);
  hipLaunchKernelGGL(gemm1_kernel, dim3(256), dim3(512), 0, stream,
                     xn16, W1gT, score, ratio, BB1, qkv);
  hipLaunchKernelGGL(attn_kernel, dim3(512), dim3(512), 0, stream,
                     qkv, ctx);
  hipLaunchKernelGGL(gemm2_kernel, dim3(256), dim3(512), 0, stream,
                     ctx, W2T, score, ratio, b_proj, (float*)d_out);
}

// Round 16
// 196.670 us; speedup vs baseline: 1.0489x; 1.0258x over previous
//
#include <hip/hip_runtime.h>
#include <stdint.h>

#define NB 4
#define SS 1024
#define DD 1024
#define EE 4
#define HH 16
#define HDD 64
#define NN (NB*SS)      // 4096 tokens
#define KK2 (EE*DD)     // 4096 expanded K
#define FF1 (3*DD)      // 3072

typedef __attribute__((ext_vector_type(4))) float f32x4;
typedef __attribute__((ext_vector_type(8))) _Float16 half8;
typedef __attribute__((ext_vector_type(4))) _Float16 half4;

static __device__ __forceinline__ f32x4 mfma16(half8 a, half8 b, f32x4 c){
  return __builtin_amdgcn_mfma_f32_16x16x32_f16(a, b, c, 0, 0, 0);
}

// async global->LDS, 16B per lane; LDS dest = wave-uniform base + lane*16
#define GLOAD_LDS16(gp, lp) __builtin_amdgcn_global_load_lds( \
    (const unsigned int __attribute__((address_space(1)))*)(uintptr_t)(gp), \
    (unsigned int __attribute__((address_space(3)))*)(uintptr_t)(lp), 16, 0, 0)

#define SBAR() do { asm volatile("" ::: "memory"); \
                    __builtin_amdgcn_s_barrier(); \
                    asm volatile("" ::: "memory"); } while(0)
#define VMC(n) asm volatile("s_waitcnt vmcnt(" #n ")" ::: "memory")

// ---------------- fused prologue: W transposes + router/LN prep -------------
__device__ __forceinline__ void prep_body(
    const float* __restrict__ x, const float* __restrict__ Wr,
    const float* __restrict__ br, float* __restrict__ score,
    float* __restrict__ ratios, _Float16* __restrict__ xnb,
    int n, float (*red)[6])
{
  int tid = threadIdx.x;
  float4 xv = ((const float4*)(x + (size_t)n*DD))[tid];   // d = tid*4..+3
  float xa[4] = {xv.x, xv.y, xv.z, xv.w};
  float vals[6];
  vals[0] = xa[0]+xa[1]+xa[2]+xa[3];
  vals[1] = xa[0]*xa[0]+xa[1]*xa[1]+xa[2]*xa[2]+xa[3]*xa[3];
  vals[2] = vals[3] = vals[4] = vals[5] = 0.f;
  #pragma unroll
  for (int j = 0; j < 4; ++j){
    float4 w = ((const float4*)Wr)[tid*4 + j];
    vals[2] += xa[j]*w.x; vals[3] += xa[j]*w.y;
    vals[4] += xa[j]*w.z; vals[5] += xa[j]*w.w;
  }
  #pragma unroll
  for (int off = 32; off >= 1; off >>= 1)
    #pragma unroll
    for (int i = 0; i < 6; ++i)
      vals[i] += __shfl_xor(vals[i], off, 64);
  int wid = tid >> 6;
  if ((tid & 63) == 0){
    #pragma unroll
    for (int i = 0; i < 6; ++i) red[wid][i] = vals[i];
  }
  __syncthreads();
  float tot[6];
  #pragma unroll
  for (int i = 0; i < 6; ++i)
    tot[i] = red[0][i] + red[1][i] + red[2][i] + red[3][i];

  float mu   = tot[0] * (1.f/DD);
  float var  = tot[1] * (1.f/DD) - mu*mu;
  float rsig = rsqrtf(var + 1e-5f);
  float lg[4];
  #pragma unroll
  for (int e = 0; e < 4; ++e) lg[e] = tot[2+e] + br[e];
  float mx = fmaxf(fmaxf(lg[0], lg[1]), fmaxf(lg[2], lg[3]));
  float ex[4], esum = 0.f;
  #pragma unroll
  for (int e = 0; e < 4; ++e){ ex[e] = __expf(lg[e] - mx); esum += ex[e]; }
  if (tid < 4){
    score[n*4 + tid] = ex[tid] / esum;
    // expert-inner telescoping: r0 = s0; r_e = s_e/s_{e-1}
    ratios[n*4 + tid] = (tid == 0) ? (ex[0] / esum) : (ex[tid] / ex[tid-1]);
  }

  half4 o;
  #pragma unroll
  for (int j = 0; j < 4; ++j) o[j] = (_Float16)((xa[j] - mu) * rsig);
  *(half4*)(xnb + (size_t)n*DD + tid*4) = o;
}

template<bool AFFINE>
__device__ __forceinline__ void transpose_body(
    const float* __restrict__ W, _Float16* __restrict__ WT, int K, int F,
    const float* __restrict__ gvec, const float* __restrict__ bvec,
    float* __restrict__ part, int k0, int f0,
    float (*t)[65], float (*red2)[64])
{
  int tid = threadIdx.x;
  int r = tid >> 4, c4 = (tid & 15) * 4;
  float pf[4] = {0.f, 0.f, 0.f, 0.f};
  #pragma unroll
  for (int i = 0; i < 4; ++i){
    int k = k0 + i*16 + r;
    float4 v = *(const float4*)(W + (size_t)k*F + f0 + c4);
    if constexpr (AFFINE){
      float bk = bvec[k];
      pf[0] += bk*v.x; pf[1] += bk*v.y; pf[2] += bk*v.z; pf[3] += bk*v.w;
      float gk = gvec[k];
      v.x *= gk; v.y *= gk; v.z *= gk; v.w *= gk;
    }
    t[i*16 + r][c4+0] = v.x; t[i*16 + r][c4+1] = v.y;
    t[i*16 + r][c4+2] = v.z; t[i*16 + r][c4+3] = v.w;
  }
  if constexpr (AFFINE){
    #pragma unroll
    for (int j = 0; j < 4; ++j) red2[r][c4+j] = pf[j];
  }
  __syncthreads();
  int f = tid >> 2, seg = tid & 3;
  half8 o0, o1;
  #pragma unroll
  for (int j = 0; j < 8; ++j){
    o0[j] = (_Float16)t[seg*16 + j][f];
    o1[j] = (_Float16)t[seg*16 + 8 + j][f];
  }
  _Float16* dst = WT + (size_t)(f0 + f)*K + k0 + seg*16;
  *(half8*)dst = o0;
  *(half8*)(dst + 8) = o1;
  if constexpr (AFFINE){
    if (tid < 64){
      float s = 0.f;
      #pragma unroll
      for (int rr = 0; rr < 16; ++rr) s += red2[rr][tid];
      part[(size_t)(k0/64) * F + f0 + tid] = s;
    }
  }
}

__global__ __launch_bounds__(256) void prep_fused_kernel(
    const float* __restrict__ W1, _Float16* __restrict__ W1T,
    const float* __restrict__ W2, _Float16* __restrict__ W2T,
    const float* __restrict__ gvec, const float* __restrict__ bvec,
    float* __restrict__ part,
    const float* __restrict__ x, const float* __restrict__ Wr,
    const float* __restrict__ br, float* __restrict__ score,
    float* __restrict__ ratios, _Float16* __restrict__ xnb)
{
  __shared__ float t[64][65];
  __shared__ float red2[16][64];
  __shared__ float red[4][6];
  int id = blockIdx.x;
  if (id & 1){
    prep_body(x, Wr, br, score, ratios, xnb, id >> 1, red);
  } else {
    int tr = id >> 1;
    int k0 = (tr & 63) * 64;
    int y  = tr >> 6;
    if (y < FF1/64)
      transpose_body<true >(W1, W1T, KK2, FF1, gvec, bvec, part, k0, y*64, t, red2);
    else
      transpose_body<false>(W2, W2T, KK2, DD, nullptr, nullptr, nullptr,
                            k0, (y - FF1/64)*64, t, red2);
  }
}

// ---------------- BB1[e,f] = b_attn[e,f] + sum_i part[e*16+i, f] ------------
__global__ __launch_bounds__(256) void bb1_kernel(
    const float* __restrict__ b_attn, const float* __restrict__ part,
    float* __restrict__ BB1)
{
  int idx = blockIdx.x*256 + threadIdx.x;   // e*FF1 + f
  int e = idx / FF1, f = idx - e*FF1;
  float s = b_attn[idx];
  #pragma unroll
  for (int i = 0; i < 16; ++i)
    s += part[(size_t)(e*16 + i)*FF1 + f];
  BB1[idx] = s;
}

// ---------------- GEMM1 (expert-inner): qkv = sum_e s_e*(xn @ W1g_e) + b ----
// [R13-best: 93.5us, FETCH 45.7MB] 256x192 tile, 8 waves (4M x 2N). Per
// d0-tile A-frags in regs once, 4 expert phases; f16 telescoping on A-frags.
// A dbuf 64 KiB; B triple 72 KiB; vmcnt {3,3,3,7}, 1 barrier/phase.
#define G1_BM 256
#define G1_BN 192
#define G1_BK 64
#define G1_NT 16                      // d0 tiles
#define G1_ABUF (G1_BM*G1_BK)         // 16384 f16 = 32 KiB
#define G1_BBUF (G1_BN*G1_BK)         // 12288 f16 = 24 KiB

__global__ __launch_bounds__(512, 2) void gemm1_kernel(
    const _Float16* __restrict__ XN, const _Float16* __restrict__ BT,
    const float* __restrict__ score, const float* __restrict__ ratios,
    const float* __restrict__ bias, _Float16* __restrict__ C)
{
  __shared__ _Float16 smA[2*G1_ABUF];   // 64 KiB
  __shared__ _Float16 smB[3*G1_BBUF];   // 72 KiB
  int tid = threadIdx.x;
  int lane = tid & 63, wid = tid >> 6;
  int q = lane & 15, g = lane >> 4;
  int wr = wid >> 1, wc = wid & 1;
  int xo = (q & 7) << 3;
  int bid = blockIdx.x;
  int xcd = bid & 7, li = bid >> 3;
  int m0 = (li >> 1) * G1_BM;
  int n0 = (xcd*2 + (li & 1)) * G1_BN;

  int arow[4], brow[6];
  #pragma unroll
  for (int mf = 0; mf < 4; ++mf) arow[mf] = (wr*64 + mf*16 + q)*64;
  #pragma unroll
  for (int nf = 0; nf < 6; ++nf) brow[nf] = (wc*96 + nf*16 + q)*64;
  int soff[2] = { (g*8) ^ xo, (32 + g*8) ^ xo };

  _Float16 rf[4][4];
  #pragma unroll
  for (int mf = 0; mf < 4; ++mf){
    float4 rr = *(const float4*)(ratios + (size_t)(m0 + wr*64 + mf*16 + q)*4);
    rf[mf][0] = (_Float16)rr.x; rf[mf][1] = (_Float16)rr.y;
    rf[mf][2] = (_Float16)rr.z; rf[mf][3] = (_Float16)rr.w;
  }

  auto stageA = [&](int t){                 // 4 loads, buf t&1
    _Float16* sA = smA + (t & 1)*G1_ABUF;
    const int d0 = t * G1_BK;
    #pragma unroll
    for (int ld = 0; ld < 4; ++ld){
      int c = ld*512 + tid;
      int row = c >> 3;
      int seg = (c & 7) ^ (row & 7);        // inverse-swizzled global source
      GLOAD_LDS16(XN + (size_t)(m0 + row)*DD + d0 + seg*8,
                  sA + (ld*512 + wid*64)*8);
    }
  };
  auto stageB = [&](int gec){               // 3 loads, buf gec%3; gec = t*4+e
    const int k0 = (gec & 3)*DD + (gec >> 2)*G1_BK;
    _Float16* sB = smB + (gec % 3)*G1_BBUF;
    #pragma unroll
    for (int ld = 0; ld < 3; ++ld){
      int c = ld*512 + tid;
      int row = c >> 3;
      int seg = (c & 7) ^ (row & 7);
      GLOAD_LDS16(BT + (size_t)(n0 + row)*KK2 + k0 + seg*8,
                  sB + (ld*512 + wid*64)*8);
    }
  };

  f32x4 acc[4][6] = {};
  half8 af[4][2];                           // A frags, live across 4 phases

  auto phase = [&](const _Float16* Ab, const _Float16* Bb,
                   _Float16 s0, _Float16 s1, _Float16 s2, _Float16 s3,
                   bool readAF){
    if (readAF){
      #pragma unroll
      for (int m = 0; m < 4; ++m)
        #pragma unroll
        for (int k = 0; k < 2; ++k)
          af[m][k] = *(const half8*)(Ab + arow[m] + soff[k]);
    }
    #pragma unroll
    for (int k = 0; k < 2; ++k)
      #pragma unroll
      for (int j = 0; j < 8; ++j){
        af[0][k][j] *= s0; af[1][k][j] *= s1;
        af[2][k][j] *= s2; af[3][k][j] *= s3;
      }
    half8 bf[3][2];
    #pragma unroll
    for (int n = 0; n < 3; ++n)
      #pragma unroll
      for (int k = 0; k < 2; ++k)
        bf[n][k] = *(const half8*)(Bb + brow[n] + soff[k]);
    __builtin_amdgcn_s_setprio(1);
    #pragma unroll
    for (int k = 0; k < 2; ++k)
      #pragma unroll
      for (int m = 0; m < 4; ++m)
        #pragma unroll
        for (int n = 0; n < 3; ++n)
          acc[m][n] = mfma16(af[m][k], bf[n][k], acc[m][n]);
    __builtin_amdgcn_s_setprio(0);
    #pragma unroll
    for (int n = 0; n < 3; ++n)
      #pragma unroll
      for (int k = 0; k < 2; ++k)
        bf[n][k] = *(const half8*)(Bb + brow[3+n] + soff[k]);
    __builtin_amdgcn_s_setprio(1);
    #pragma unroll
    for (int k = 0; k < 2; ++k)
      #pragma unroll
      for (int m = 0; m < 4; ++m)
        #pragma unroll
        for (int n = 0; n < 3; ++n)
          acc[m][3+n] = mfma16(af[m][k], bf[n][k], acc[m][3+n]);
    __builtin_amdgcn_s_setprio(0);
  };

  stageA(0); stageB(0); stageB(1);

  #pragma unroll 1
  for (int t = 0; t < G1_NT-1; ++t){
    const _Float16* Ab = smA + (t & 1)*G1_ABUF;
    int g4 = t*4;
    VMC(3); SBAR();
    stageB(g4+2);
    phase(Ab, smB + (g4 % 3)*G1_BBUF, rf[0][0], rf[1][0], rf[2][0], rf[3][0], true);
    VMC(3); SBAR();
    stageB(g4+3);
    phase(Ab, smB + ((g4+1) % 3)*G1_BBUF, rf[0][1], rf[1][1], rf[2][1], rf[3][1], false);
    VMC(3); SBAR();
    stageB(g4+4); stageA(t+1);
    phase(Ab, smB + ((g4+2) % 3)*G1_BBUF, rf[0][2], rf[1][2], rf[2][2], rf[3][2], false);
    VMC(7); SBAR();
    stageB(g4+5);
    phase(Ab, smB + ((g4+3) % 3)*G1_BBUF, rf[0][3], rf[1][3], rf[2][3], rf[3][3], false);
  }
  {
    const _Float16* Ab = smA + ((G1_NT-1) & 1)*G1_ABUF;
    VMC(3); SBAR();
    stageB(62);
    phase(Ab, smB + (60 % 3)*G1_BBUF, rf[0][0], rf[1][0], rf[2][0], rf[3][0], true);
    VMC(3); SBAR();
    stageB(63);
    phase(Ab, smB + (61 % 3)*G1_BBUF, rf[0][1], rf[1][1], rf[2][1], rf[3][1], false);
    VMC(3); SBAR();
    phase(Ab, smB + (62 % 3)*G1_BBUF, rf[0][2], rf[1][2], rf[2][2], rf[3][2], false);
    VMC(0); SBAR();
    phase(Ab, smB + (63 % 3)*G1_BBUF, rf[0][3], rf[1][3], rf[2][3], rf[3][3], false);
  }

  // epilogue: acc includes all s_e; add sum_e score*BB1, f16 store
  float bv[6][4];
  #pragma unroll
  for (int nf = 0; nf < 6; ++nf){
    int gn = n0 + wc*96 + nf*16 + q;
    #pragma unroll
    for (int e = 0; e < 4; ++e) bv[nf][e] = bias[e*FF1 + gn];
  }
  #pragma unroll
  for (int mf = 0; mf < 4; ++mf){
    #pragma unroll
    for (int r = 0; r < 4; ++r){
      int gm = m0 + wr*64 + mf*16 + g*4 + r;
      float4 sc = *(const float4*)(score + gm*4);
      #pragma unroll
      for (int nf = 0; nf < 6; ++nf){
        int gn = n0 + wc*96 + nf*16 + q;
        float v = acc[mf][nf][r]
                + sc.x*bv[nf][0] + sc.y*bv[nf][1] + sc.z*bv[nf][2] + sc.w*bv[nf][3];
        C[(size_t)gm*FF1 + gn] = (_Float16)v;
      }
    }
  }
}

// ---------------- GEMM2: out = sum_e s_e*(ctx @ W2_e) + bias ----------------
// [R13 config] 128x128 tile, BK=64, 8 waves (2M x 4N), dbuf, counted
// vmcnt(4), 2-phase compute with kk1-reads hoisted. Per-expert acc split.
#define G2_BK 64
#define G2_ABUF (128*G2_BK)
#define G2_BUFSZ (2*G2_ABUF)         // A+B per buffer = 32 KiB

__global__ __launch_bounds__(512) void gemm2_kernel(
    const _Float16* __restrict__ CTX, const _Float16* __restrict__ BT,
    const float* __restrict__ score, const float* __restrict__ bias,
    float* __restrict__ Cout)
{
  __shared__ _Float16 smem[2*G2_BUFSZ];   // 64 KiB
  int tid = threadIdx.x;
  int lane = tid & 63, wid = tid >> 6;
  int q = lane & 15, g = lane >> 4;
  int wr = wid >> 2, wc = wid & 3;     // 2M x 4N
  int xo = (q & 7) << 3;
  int bid = blockIdx.x;
  int xcd = bid >> 5, idx = bid & 31;
  int m0 = (xcd*4 + (idx >> 3)) * 128;
  int n0 = (idx & 7) * 128;

  int arow[4], brow[2];
  #pragma unroll
  for (int mf = 0; mf < 4; ++mf) arow[mf] = (wr*64 + mf*16 + q)*64;
  #pragma unroll
  for (int nf = 0; nf < 2; ++nf) brow[nf] = G2_ABUF + (wc*32 + nf*16 + q)*64;
  int soff[2] = { (g*8) ^ xo, (32 + g*8) ^ xo };

  auto stage = [&](int t, int buf){
    const int d0 = (t & 15) * G2_BK;
    const int k0 = t * G2_BK;
    _Float16* sA = smem + buf*G2_BUFSZ;
    _Float16* sB = sA + G2_ABUF;
    #pragma unroll
    for (int ld = 0; ld < 2; ++ld){
      int c = ld*512 + tid;
      int row = c >> 3;
      int seg = (c & 7) ^ (row & 7);
      GLOAD_LDS16(CTX + (size_t)(m0 + row)*DD + d0 + seg*8,
                  sA + (ld*512 + wid*64)*8);
    }
    #pragma unroll
    for (int ld = 0; ld < 2; ++ld){
      int c = ld*512 + tid;
      int row = c >> 3;
      int seg = (c & 7) ^ (row & 7);
      GLOAD_LDS16(BT + (size_t)(n0 + row)*KK2 + k0 + seg*8,
                  sB + (ld*512 + wid*64)*8);
    }
  };

  f32x4 accp[4][2] = {}, acco[4][2] = {};

  auto merge = [&](int e){
    #pragma unroll
    for (int m = 0; m < 4; ++m)
      #pragma unroll
      for (int r = 0; r < 4; ++r){
        int gm = m0 + wr*64 + m*16 + g*4 + r;
        float s = score[(size_t)gm*4 + e];
        #pragma unroll
        for (int n = 0; n < 2; ++n){
          acco[m][n][r] += s*accp[m][n][r];
          accp[m][n][r] = 0.f;
        }
      }
  };

  half8 af[4][2], bfr[2][2];
  auto reads = [&](const _Float16* base, int k){
    #pragma unroll
    for (int m = 0; m < 4; ++m)
      af[m][k] = *(const half8*)(base + arow[m] + soff[k]);
    #pragma unroll
    for (int n = 0; n < 2; ++n)
      bfr[n][k] = *(const half8*)(base + brow[n] + soff[k]);
  };
  auto mfmas = [&](int k){
    __builtin_amdgcn_s_setprio(1);
    #pragma unroll
    for (int m = 0; m < 4; ++m)
      #pragma unroll
      for (int n = 0; n < 2; ++n)
        accp[m][n] = mfma16(af[m][k], bfr[n][k], accp[m][n]);
    __builtin_amdgcn_s_setprio(0);
  };

  stage(0, 0);
  for (int t = 0; t < KK2/G2_BK - 1; ++t){
    const _Float16* base = smem + (t & 1)*G2_BUFSZ;
    stage(t+1, (t+1)&1);
    asm volatile("s_waitcnt vmcnt(4)" ::: "memory");  // tile t landed
    SBAR();
    reads(base, 0);
    mfmas(0);
    reads(base, 1);            // hoisted pre-barrier
    SBAR();                    // reads of buf(t) all issued -> restage safe next iter
    mfmas(1);
    if ((t & 15) == 15) merge(t >> 4);                // expert boundary
  }
  {
    const _Float16* base = smem + ((KK2/G2_BK - 1) & 1)*G2_BUFSZ;
    asm volatile("s_waitcnt vmcnt(0)" ::: "memory");
    SBAR();
    reads(base, 0); reads(base, 1);
    mfmas(0); mfmas(1);
    merge(3);
  }

  #pragma unroll
  for (int m = 0; m < 4; ++m){
    #pragma unroll
    for (int r = 0; r < 4; ++r){
      int gm = m0 + wr*64 + m*16 + g*4 + r;
      float4 sc = *(const float4*)(score + gm*4);
      #pragma unroll
      for (int n = 0; n < 2; ++n){
        int gn = n0 + wc*32 + n*16 + q;
        float v = acco[m][n][r]
                + sc.x*bias[gn] + sc.y*bias[DD+gn]
                + sc.z*bias[2*DD+gn] + sc.w*bias[3*DD+gn];
        Cout[(size_t)gm*DD + gn] = v;
      }
    }
  }
}

// ---------------- kernel 4: causal flash attention, QBLK=128, 8 waves -------
__global__ __launch_bounds__(512) void attn_kernel(
    const _Float16* __restrict__ qkv, _Float16* __restrict__ ctx)
{
  __shared__ _Float16 lsK[2][64*64];   // [key][hd], swizzled
  __shared__ _Float16 lsV[2][64*64];   // [hd][key], swizzled (transposed)
  __shared__ _Float16 lsP[8][16*64];   // per-wave P [qrow][key], swizzled
  int id = blockIdx.x;                 // 0..511
  int p = id >> 1, parity = id & 1;
  int bh = p & 63;
  int qtp = p >> 6;                    // 0..3
  int qt = parity ? qtp : 7 - qtp;     // pair (7-qtp, qtp): tiles sum = 18
  int b = bh >> 4, h = bh & 15;
  int tid = threadIdx.x, lane = tid & 63, wid = tid >> 6;   // wid 0..7
  int q = lane & 15, g = lane >> 4;
  int xo = (q & 7) << 3;
  int qrow0 = qt*128 + wid*16;

  half8 qf[2];
  #pragma unroll
  for (int kk = 0; kk < 2; ++kk)
    qf[kk] = *(const half8*)(qkv + ((size_t)b*SS + qrow0 + q)*FF1 + h*HDD + kk*32 + g*8);

  auto issueK = [&](int kt, int buf){
    size_t kvrow = (size_t)b*SS + kt*64;
    int row = tid >> 3, seg = (tid & 7) ^ (row & 7);
    GLOAD_LDS16(qkv + (kvrow + row)*FF1 + DD + h*HDD + seg*8,
                lsK[buf] + (size_t)(wid*64)*8);
  };
  auto issueV = [&](int kt, half8& vr){
    size_t kvrow = (size_t)b*SS + kt*64;
    vr = *(const half8*)(qkv + (kvrow + lane)*FF1 + 2*DD + h*HDD + wid*8);
  };
  auto writeV = [&](half8 vr, int buf){
    #pragma unroll
    for (int j = 0; j < 8; ++j){
      int hd = wid*8 + j;
      lsV[buf][hd*64 + (lane ^ ((hd & 7) << 3))] = vr[j];
    }
  };

  f32x4 o[4] = {};
  float mrow = -1e30f, lsum = 0.f;     // stats for qrow = q (log2 domain)
  const float SC2 = 0.18033688011112042f;  // log2(e)/8
  int qglob = qrow0 + q;
  int ktmax = 2*qt + 1;

  half8 vr;
  issueK(0, 0);
  issueV(0, vr);

  for (int kt = 0; kt <= ktmax; ++kt){
    int cur = kt & 1, nxt = cur ^ 1;
    int tn = (kt < ktmax) ? kt+1 : ktmax;
    bool active = (kt*64 <= qrow0 + 15);
    asm volatile("s_waitcnt vmcnt(1)" ::: "memory");
    SBAR();

    f32x4 st[4] = {};
    if (active){
      __builtin_amdgcn_s_setprio(1);
      #pragma unroll
      for (int i = 0; i < 4; ++i){
        #pragma unroll
        for (int kk = 0; kk < 2; ++kk){
          half8 kf = *(const half8*)(lsK[cur] + (i*16 + q)*64 + ((kk*32 + g*8) ^ xo));
          st[i] = mfma16(kf, qf[kk], st[i]);
        }
      }
      __builtin_amdgcn_s_setprio(0);
    }
    issueK(tn, nxt);
    asm volatile("s_waitcnt vmcnt(1)" ::: "memory");
    writeV(vr, cur);

    _Float16 pb[16];
    bool resc = false;
    float psum = 0.f;
    if (active){
      float pvv[16]; float tm = -1e30f;
      if (kt*64 + 63 > qrow0){
        #pragma unroll
        for (int i = 0; i < 4; ++i)
          #pragma unroll
          for (int r = 0; r < 4; ++r){
            int kglob = kt*64 + i*16 + g*4 + r;
            float sv = (kglob <= qglob) ? st[i][r]*SC2 : -1e30f;
            pvv[i*4+r] = sv; tm = fmaxf(tm, sv);
          }
      } else {
        #pragma unroll
        for (int i = 0; i < 4; ++i)
          #pragma unroll
          for (int r = 0; r < 4; ++r){
            float sv = st[i][r]*SC2;
            pvv[i*4+r] = sv; tm = fmaxf(tm, sv);
          }
      }
      tm = fmaxf(tm, __shfl_xor(tm, 16, 64));
      tm = fmaxf(tm, __shfl_xor(tm, 32, 64));
      resc = !__all(tm <= mrow);
      float mnew = resc ? fmaxf(mrow, tm) : mrow;
      #pragma unroll
      for (int i = 0; i < 16; ++i){
        float p2 = exp2f(pvv[i] - mnew);
        psum += p2; pb[i] = (_Float16)p2;
      }
      if (resc){
        float alpha = exp2f(mrow - mnew);
        mrow = mnew;
        lsum = lsum*alpha + psum;
        float af4[4];
        #pragma unroll
        for (int r = 0; r < 4; ++r) af4[r] = __shfl(alpha, g*4 + r, 64);
        #pragma unroll
        for (int n = 0; n < 4; ++n)
          #pragma unroll
          for (int r = 0; r < 4; ++r) o[n][r] *= af4[r];
      } else {
        lsum += psum;
      }
    }
    issueV(tn, vr);

    asm volatile("s_waitcnt lgkmcnt(0)" ::: "memory");
    SBAR();

    if (active){
      #pragma unroll
      for (int i = 0; i < 4; ++i){
        half4 w4;
        w4[0]=pb[i*4+0]; w4[1]=pb[i*4+1]; w4[2]=pb[i*4+2]; w4[3]=pb[i*4+3];
        *(half4*)(&lsP[wid][q*64 + ((i*16 + g*4) ^ xo)]) = w4;
      }
      __builtin_amdgcn_s_setprio(1);
      #pragma unroll
      for (int kk = 0; kk < 2; ++kk){
        half8 pf = *(const half8*)(&lsP[wid][q*64 + ((kk*32 + g*8) ^ xo)]);
        #pragma unroll
        for (int n = 0; n < 4; ++n){
          half8 vf = *(const half8*)(&lsV[cur][(n*16 + q)*64 + ((kk*32 + g*8) ^ xo)]);
          o[n] = mfma16(pf, vf, o[n]);
        }
      }
      __builtin_amdgcn_s_setprio(0);
    }
  }
  float lt = lsum + __shfl_xor(lsum, 16, 64);
  lt = lt + __shfl_xor(lt, 32, 64);
  float rinv = 1.f / lt;
  #pragma unroll
  for (int r = 0; r < 4; ++r){
    float ri = __shfl(rinv, g*4 + r, 64);
    int qg = qt*128 + wid*16 + g*4 + r;
    _Float16* obase = ctx + ((size_t)b*SS + qg)*DD + h*HDD;
    #pragma unroll
    for (int n = 0; n < 4; ++n)
      obase[n*16 + q] = (_Float16)(o[n][r] * ri);
  }
}

// ---------------------------------------------------------------------------
extern "C" void kernel_launch(void* const* d_in, const int* in_sizes, int n_in,
                              void* d_out, int out_size, void* d_ws, size_t ws_size,
                              hipStream_t stream)
{
  const float* x      = (const float*)d_in[0];
  const float* Wr     = (const float*)d_in[1];
  const float* br     = (const float*)d_in[2];
  const float* ln_g   = (const float*)d_in[3];
  const float* ln_b   = (const float*)d_in[4];
  const float* W_attn = (const float*)d_in[5];
  const float* b_attn = (const float*)d_in[6];
  const float* W_proj = (const float*)d_in[7];
  const float* b_proj = (const float*)d_in[8];
  (void)in_sizes; (void)n_in; (void)out_size; (void)ws_size;

  char* ws = (char*)d_ws;
  size_t off = 0;
  auto alloc = [&](size_t bytes) -> void* {
    void* p = ws + off; off += (bytes + 255) & ~(size_t)255; return p;
  };
  _Float16* W1gT  = (_Float16*)alloc((size_t)FF1*KK2*2);   // 25.2 MB (g folded)
  _Float16* W2T   = (_Float16*)alloc((size_t)DD*KK2*2);    //  8.4 MB
  float*    score = (float*)   alloc((size_t)NN*4*4);      // 64 KB
  float*    ratio = (float*)   alloc((size_t)NN*4*4);      // 64 KB
  _Float16* xn16  = (_Float16*)alloc((size_t)NN*DD*2);     //  8.4 MB
  _Float16* qkv   = (_Float16*)alloc((size_t)NN*FF1*2);    // 25.2 MB
  _Float16* ctx   = (_Float16*)alloc((size_t)NN*DD*2);     //  8.4 MB
  float*    part  = (float*)   alloc((size_t)(KK2/64)*FF1*4); // 786 KB
  float*    BB1   = (float*)   alloc((size_t)EE*FF1*4);    // 48 KB

  hipLaunchKernelGGL(prep_fused_kernel, dim3(8192), dim3(256), 0, stream,
                     W_attn, W1gT, W_proj, W2T, ln_g, ln_b, part,
                     x, Wr, br, score, ratio, xn16);
  hipLaunchKernelGGL(bb1_kernel, dim3(EE*FF1/256), dim3(256), 0, stream,
                     b_attn, part, BB1);
  hipLaunchKernelGGL(gemm1_kernel, dim3(256), dim3(512), 0, stream,
                     xn16, W1gT, score, ratio, BB1, qkv);
  hipLaunchKernelGGL(attn_kernel, dim3(512), dim3(512), 0, stream,
                     qkv, ctx);
  hipLaunchKernelGGL(gemm2_kernel, dim3(256), dim3(512), 0, stream,
                     ctx, W2T, score, b_proj, (float*)d_out);
}